// Round 1
// baseline (400.034 us; speedup 1.0000x reference)
//
#include <hip/hip_runtime.h>
#include <hip/hip_bf16.h>

#define NN 8192
#define FIN 128
#define FOUT 64
#define JCH 256      // columns per chunk
#define NCH 32       // chunks (NCH*JCH == NN)

typedef __attribute__((ext_vector_type(8))) short short8;
typedef __attribute__((ext_vector_type(4))) float floatx4;
typedef __attribute__((ext_vector_type(4))) int intx4;

__device__ __forceinline__ short f2bf_rne(float x) {
  union { float f; unsigned u; } c; c.f = x;
  unsigned r = c.u + 0x7fffu + ((c.u >> 16) & 1u);
  return (short)(r >> 16);
}
__device__ __forceinline__ float bf2f(short b) {
  union { unsigned u; float f; } c; c.u = ((unsigned)(unsigned short)b) << 16;
  return c.f;
}

// Kernel A: h = x @ W^T (fp32), s_src/s_dst, and Hb = bf16 h pre-swizzled into
// MFMA-B-fragment order: Hb[((c*4 + ftile)*64 + quad*16 + fi)*8 + v] = h[c*32+quad*8+v][ftile*16+fi]
__global__ __launch_bounds__(256) void prep_kernel(
    const float* __restrict__ x, const float* __restrict__ W,
    const float* __restrict__ att_w,
    short* __restrict__ Hb, float* __restrict__ s_src, float* __restrict__ s_dst) {
  __shared__ float xs[16 * FIN];  // 8 KB: 16 rows of x
  const int t = threadIdx.x;
  const int bid = blockIdx.x;
#pragma unroll
  for (int i = 0; i < 8; ++i)
    xs[t + i * 256] = x[(size_t)bid * (16 * FIN) + t + i * 256];
  __syncthreads();
  const int w = t >> 6;     // wave handles rows w*4 .. w*4+3
  const int f = t & 63;     // lane == output feature
  const float4* Wf4 = (const float4*)(W + f * FIN);
  const float4* xr0 = (const float4*)(xs + (w * 4 + 0) * FIN);
  const float4* xr1 = (const float4*)(xs + (w * 4 + 1) * FIN);
  const float4* xr2 = (const float4*)(xs + (w * 4 + 2) * FIN);
  const float4* xr3 = (const float4*)(xs + (w * 4 + 3) * FIN);
  float h0 = 0.f, h1 = 0.f, h2 = 0.f, h3 = 0.f;
#pragma unroll
  for (int k = 0; k < FIN / 4; ++k) {
    float4 wv = Wf4[k];
    float4 v0 = xr0[k], v1 = xr1[k], v2 = xr2[k], v3 = xr3[k];
    h0 = fmaf(v0.x, wv.x, h0); h0 = fmaf(v0.y, wv.y, h0);
    h0 = fmaf(v0.z, wv.z, h0); h0 = fmaf(v0.w, wv.w, h0);
    h1 = fmaf(v1.x, wv.x, h1); h1 = fmaf(v1.y, wv.y, h1);
    h1 = fmaf(v1.z, wv.z, h1); h1 = fmaf(v1.w, wv.w, h1);
    h2 = fmaf(v2.x, wv.x, h2); h2 = fmaf(v2.y, wv.y, h2);
    h2 = fmaf(v2.z, wv.z, h2); h2 = fmaf(v2.w, wv.w, h2);
    h3 = fmaf(v3.x, wv.x, h3); h3 = fmaf(v3.y, wv.y, h3);
    h3 = fmaf(v3.z, wv.z, h3); h3 = fmaf(v3.w, wv.w, h3);
  }
  const float asrc = att_w[f];
  const float adst = att_w[FOUT + f];
  float hv[4] = {h0, h1, h2, h3};
#pragma unroll
  for (int g = 0; g < 4; ++g) {
    float v1 = hv[g] * asrc;
    float v2 = hv[g] * adst;
#pragma unroll
    for (int off = 32; off > 0; off >>= 1) {
      v1 += __shfl_xor(v1, off, 64);
      v2 += __shfl_xor(v2, off, 64);
    }
    const int r = bid * 16 + w * 4 + g;
    if (f == 0) { s_src[r] = v1; s_dst[r] = v2; }
    const int c = r >> 5;
    const int quad = (r >> 3) & 3;
    const int vv = r & 7;
    const int tile = f >> 4;
    const int fi = f & 15;
    Hb[(((c * 4 + tile) * 64) + quad * 16 + fi) * 8 + vv] = f2bf_rne(hv[g]);
  }
}

// p for 8 consecutive columns of one row, directly in A-fragment lane layout.
__device__ __forceinline__ short8 pcalc8(float ss, intx4 lo, intx4 hi,
                                         float4 s0, float4 s1, float& dsum) {
  float sv[8] = {s0.x, s0.y, s0.z, s0.w, s1.x, s1.y, s1.z, s1.w};
  int av[8] = {lo.x, lo.y, lo.z, lo.w, hi.x, hi.y, hi.z, hi.w};
  short8 r;
#pragma unroll
  for (int v = 0; v < 8; ++v) {
    float tt = ss + sv[v];
    float e = fmaxf(tt, 0.f) + 0.01f * fminf(tt, 0.f);  // leaky_relu
    float p = __expf(e);
    p = (av[v] > 0) ? p : 0.f;
    short bb = f2bf_rne(p);
    r[v] = bb;
    dsum += bf2f(bb);  // denominator from bf16-rounded weight: exact normalization
  }
  return r;
}

// gat v3: barrier-free main loop. Wave w owns the 32-col strip (cc*256+w*32)
// for ALL 16 rows of the block: lane (quad,m) loads adj[i0+m][j0+quad*8..+8],
// computes its 8 p-values and packs bf16 -> that IS the MFMA A-fragment
// (lane quad*16+m holds A[m][quad*8+v]). No Pbuf, no cross-wave exchange, no
// __syncthreads in the loop => the adj prefetch (2-deep register pipeline) is
// never drained by a barrier's vmcnt(0); Hb (L2) issued before adj (HBM) each
// iteration so the MFMA's wait never couples to the slow stream. s_dst staged
// once in LDS (kills redundant L2 traffic; reads are quad-broadcast, 0-conflict).
__global__ __launch_bounds__(512, 4) void gat_kernel(
    const int* __restrict__ adj, const short8* __restrict__ Hb,
    const float* __restrict__ s_src, const float* __restrict__ s_dst,
    float* __restrict__ out) {
  __shared__ float shbuf[8192];      // 32 KB: s_dst in main loop, part[] in epilogue
  __shared__ float dpart[8][16];     // per-wave row-denominator partials
  float* sdl = shbuf;
  float (*part)[16][64] = (float (*)[16][64])shbuf;

  const int tid = threadIdx.x;
  const int w = tid >> 6;
  const int lane = tid & 63;
  const int m = lane & 15;
  const int quad = lane >> 4;
  const int bid = blockIdx.x;
  const int i0 = bid * 16;

  // stage s_dst (32 KB) into LDS
  for (int i = tid; i < NN / 4; i += 512)
    ((float4*)sdl)[i] = ((const float4*)s_dst)[i];

  const float ss = s_src[i0 + m];
  const int* aptr = adj + (size_t)(i0 + m) * NN + quad * 8;

  floatx4 acc0 = {0.f, 0.f, 0.f, 0.f};
  floatx4 acc1 = acc0, acc2 = acc0, acc3 = acc0;
  float dsum = 0.f;

  // prologue: adj for chunks 0,1; Hb for chunk 0
  intx4 aLoA, aHiA, aLoB, aHiB;
  short8 hA0, hA1, hA2, hA3, hB0, hB1, hB2, hB3;
  {
    const int cc0 = bid & (NCH - 1);
    const short8* hp = Hb + (size_t)(cc0 * 8 + w) * 256 + lane;
    hA0 = hp[0]; hA1 = hp[64]; hA2 = hp[128]; hA3 = hp[192];
    const intx4* ap0 = (const intx4*)(aptr + cc0 * JCH + w * 32);
    aLoA = __builtin_nontemporal_load(ap0);
    aHiA = __builtin_nontemporal_load(ap0 + 1);
    const int cc1 = (bid + 1) & (NCH - 1);
    const intx4* ap1 = (const intx4*)(aptr + cc1 * JCH + w * 32);
    aLoB = __builtin_nontemporal_load(ap1);
    aHiB = __builtin_nontemporal_load(ap1 + 1);
  }
  __syncthreads();  // sdl ready (one-time vmcnt drain, amortized)

  // per-chunk body: sv from LDS; issue next Hb (older in queue); compute
  // A-fragment (waits adj issued 2 iters ago); issue adj +2; MFMA (waits Hb).
#define CHUNK(C_, ALO, AHI, H0c, H1c, H2c, H3c, H0n, H1n, H2n, H3n)            \
  {                                                                            \
    const int cc_ = ((C_) + bid) & (NCH - 1);                                  \
    const int j0_ = cc_ * JCH + w * 32 + quad * 8;                             \
    float4 sv0_ = *(const float4*)&sdl[j0_];                                   \
    float4 sv1_ = *(const float4*)&sdl[j0_ + 4];                               \
    if ((C_) + 1 < NCH) {                                                      \
      const int cn_ = ((C_) + 1 + bid) & (NCH - 1);                            \
      const short8* hp_ = Hb + (size_t)(cn_ * 8 + w) * 256 + lane;             \
      H0n = hp_[0]; H1n = hp_[64]; H2n = hp_[128]; H3n = hp_[192];             \
    }                                                                          \
    short8 af_ = pcalc8(ss, ALO, AHI, sv0_, sv1_, dsum);                       \
    if ((C_) + 2 < NCH) {                                                      \
      const int cl_ = ((C_) + 2 + bid) & (NCH - 1);                            \
      const intx4* ap_ = (const intx4*)(aptr + cl_ * JCH + w * 32);            \
      ALO = __builtin_nontemporal_load(ap_);                                   \
      AHI = __builtin_nontemporal_load(ap_ + 1);                               \
    }                                                                          \
    acc0 = __builtin_amdgcn_mfma_f32_16x16x32_bf16(af_, H0c, acc0, 0, 0, 0);   \
    acc1 = __builtin_amdgcn_mfma_f32_16x16x32_bf16(af_, H1c, acc1, 0, 0, 0);   \
    acc2 = __builtin_amdgcn_mfma_f32_16x16x32_bf16(af_, H2c, acc2, 0, 0, 0);   \
    acc3 = __builtin_amdgcn_mfma_f32_16x16x32_bf16(af_, H3c, acc3, 0, 0, 0);   \
  }

  for (int cp = 0; cp < NCH / 2; ++cp) {
    const int c0 = 2 * cp;
    CHUNK(c0,     aLoA, aHiA, hA0, hA1, hA2, hA3, hB0, hB1, hB2, hB3)
    CHUNK(c0 + 1, aLoB, aHiB, hB0, hB1, hB2, hB3, hA0, hA1, hA2, hA3)
  }
#undef CHUNK

  // row-denominator: lane (quad,m) holds row-m partial over its col subsets;
  // sum over the 4 quads -> full wave partial for row m.
  dsum += __shfl_xor(dsum, 16, 64);
  dsum += __shfl_xor(dsum, 32, 64);

  __syncthreads();  // all waves done reading sdl; shbuf becomes part[]
  if (lane < 16) dpart[w][lane] = dsum;

  // C/D layout: col = lane&15 (feature within tile), row = quad*4 + reg
  const int col = lane & 15;
#pragma unroll
  for (int rg = 0; rg < 4; ++rg) {
    part[w][quad * 4 + rg][col]      = acc0[rg];
    part[w][quad * 4 + rg][16 + col] = acc1[rg];
    part[w][quad * 4 + rg][32 + col] = acc2[rg];
    part[w][quad * 4 + rg][48 + col] = acc3[rg];
  }
  __syncthreads();

  // epilogue: sum 8 wave-partials (disjoint j), normalize, ELU, coalesced store
  for (int idx = tid; idx < 16 * 64; idx += 512) {
    int mr = idx >> 6, fc = idx & 63;
    float num = 0.f, den = 0.f;
#pragma unroll
    for (int ww = 0; ww < 8; ++ww) { num += part[ww][mr][fc]; den += dpart[ww][mr]; }
    float o = num / den;
    o = (o > 0.f) ? o : (__expf(o) - 1.f);
    out[(size_t)(i0 + mr) * FOUT + fc] = o;
  }
}

extern "C" void kernel_launch(void* const* d_in, const int* in_sizes, int n_in,
                              void* d_out, int out_size, void* d_ws, size_t ws_size,
                              hipStream_t stream) {
  const float* x     = (const float*)d_in[0];
  const int*   adj   = (const int*)d_in[1];
  const float* W     = (const float*)d_in[2];
  const float* att_w = (const float*)d_in[3];
  float* out = (float*)d_out;
  char* ws = (char*)d_ws;
  short* Hb = (short*)ws;                                   // 1 MB bf16 swizzled h
  float* s_src = (float*)(ws + (size_t)NN * FOUT * sizeof(short));
  float* s_dst = s_src + NN;
  prep_kernel<<<NN / 16, 256, 0, stream>>>(x, W, att_w, Hb, s_src, s_dst);
  gat_kernel<<<NN / 16, 512, 0, stream>>>(adj, (const short8*)Hb, s_src, s_dst, out);
}

// Round 2
// 380.576 us; speedup vs baseline: 1.0511x; 1.0511x over previous
//
#include <hip/hip_runtime.h>
#include <hip/hip_bf16.h>

#define NN 8192
#define FIN 128
#define FOUT 64
#define JCH 256      // columns per chunk
#define NCH 32       // chunks (NCH*JCH == NN)
#define PSTR 264     // Pbuf row stride in shorts: 256 + 8 pad (2-way-free banks)

typedef __attribute__((ext_vector_type(8))) short short8;
typedef __attribute__((ext_vector_type(4))) short short4v;
typedef __attribute__((ext_vector_type(4))) float floatx4;
typedef __attribute__((ext_vector_type(4))) int intx4;

__device__ __forceinline__ short f2bf_rne(float x) {
  union { float f; unsigned u; } c; c.f = x;
  unsigned r = c.u + 0x7fffu + ((c.u >> 16) & 1u);
  return (short)(r >> 16);
}
__device__ __forceinline__ float bf2f(short b) {
  union { unsigned u; float f; } c; c.u = ((unsigned)(unsigned short)b) << 16;
  return c.f;
}

// Kernel A: h = x @ W^T (fp32), s_src/s_dst, and Hb = bf16 h pre-swizzled into
// MFMA-B-fragment order: Hb[((c*4 + ftile)*64 + quad*16 + fi)*8 + v] = h[c*32+quad*8+v][ftile*16+fi]
__global__ __launch_bounds__(256) void prep_kernel(
    const float* __restrict__ x, const float* __restrict__ W,
    const float* __restrict__ att_w,
    short* __restrict__ Hb, float* __restrict__ s_src, float* __restrict__ s_dst) {
  __shared__ float xs[16 * FIN];  // 8 KB: 16 rows of x
  const int t = threadIdx.x;
  const int bid = blockIdx.x;
#pragma unroll
  for (int i = 0; i < 8; ++i)
    xs[t + i * 256] = x[(size_t)bid * (16 * FIN) + t + i * 256];
  __syncthreads();
  const int w = t >> 6;     // wave handles rows w*4 .. w*4+3
  const int f = t & 63;     // lane == output feature
  const float4* Wf4 = (const float4*)(W + f * FIN);
  const float4* xr0 = (const float4*)(xs + (w * 4 + 0) * FIN);
  const float4* xr1 = (const float4*)(xs + (w * 4 + 1) * FIN);
  const float4* xr2 = (const float4*)(xs + (w * 4 + 2) * FIN);
  const float4* xr3 = (const float4*)(xs + (w * 4 + 3) * FIN);
  float h0 = 0.f, h1 = 0.f, h2 = 0.f, h3 = 0.f;
#pragma unroll
  for (int k = 0; k < FIN / 4; ++k) {
    float4 wv = Wf4[k];
    float4 v0 = xr0[k], v1 = xr1[k], v2 = xr2[k], v3 = xr3[k];
    h0 = fmaf(v0.x, wv.x, h0); h0 = fmaf(v0.y, wv.y, h0);
    h0 = fmaf(v0.z, wv.z, h0); h0 = fmaf(v0.w, wv.w, h0);
    h1 = fmaf(v1.x, wv.x, h1); h1 = fmaf(v1.y, wv.y, h1);
    h1 = fmaf(v1.z, wv.z, h1); h1 = fmaf(v1.w, wv.w, h1);
    h2 = fmaf(v2.x, wv.x, h2); h2 = fmaf(v2.y, wv.y, h2);
    h2 = fmaf(v2.z, wv.z, h2); h2 = fmaf(v2.w, wv.w, h2);
    h3 = fmaf(v3.x, wv.x, h3); h3 = fmaf(v3.y, wv.y, h3);
    h3 = fmaf(v3.z, wv.z, h3); h3 = fmaf(v3.w, wv.w, h3);
  }
  const float asrc = att_w[f];
  const float adst = att_w[FOUT + f];
  float hv[4] = {h0, h1, h2, h3};
#pragma unroll
  for (int g = 0; g < 4; ++g) {
    float v1 = hv[g] * asrc;
    float v2 = hv[g] * adst;
#pragma unroll
    for (int off = 32; off > 0; off >>= 1) {
      v1 += __shfl_xor(v1, off, 64);
      v2 += __shfl_xor(v2, off, 64);
    }
    const int r = bid * 16 + w * 4 + g;
    if (f == 0) { s_src[r] = v1; s_dst[r] = v2; }
    const int c = r >> 5;
    const int quad = (r >> 3) & 3;
    const int vv = r & 7;
    const int tile = f >> 4;
    const int fi = f & 15;
    Hb[(((c * 4 + tile) * 64) + quad * 16 + fi) * 8 + vv] = f2bf_rne(hv[g]);
  }
}

// p for 4 consecutive columns of one row; returns packed bf16, accumulates denominator
__device__ __forceinline__ short4v pcalc(float ssrc, intx4 a, float4 s, float& dsum) {
  float sv[4] = {s.x, s.y, s.z, s.w};
  int av[4] = {a.x, a.y, a.z, a.w};
  short4v r;
#pragma unroll
  for (int v = 0; v < 4; ++v) {
    float tt = ssrc + sv[v];
    float e = fmaxf(tt, 0.f) + 0.01f * fminf(tt, 0.f);  // leaky_relu
    float p = __expf(e);
    p = (av[v] > 0) ? p : 0.f;
    short bb = f2bf_rne(p);
    r[v] = bb;
    dsum += bf2f(bb);  // denominator from bf16-rounded weight: exact normalization
  }
  return r;
}

// gat v4 = v2 structure (coalesced adj, LDS p-exchange) + CHEAP BARRIER:
// the loop barrier is `s_waitcnt lgkmcnt(0); s_barrier` via inline asm instead
// of __syncthreads(), so the compiler's vmcnt(0) full-drain never happens in
// the main loop. LDS p-writes are made cross-wave-visible (lgkmcnt(0) covers
// all ds ops), while the adj/sv/Hb global prefetches stay IN FLIGHT across the
// barrier and get counted vmcnt waits at their use (AITER pattern: never
// vmcnt(0) in the loop). Double-buffer hazard: buf (c+1)&1 is last READ in
// iter c-1 (ds_reads drained by the same lgkmcnt(0)) and WRITTEN after
// barrier c -> safe.
__global__ __launch_bounds__(512, 4) void gat_kernel(
    const int* __restrict__ adj, const short8* __restrict__ Hb,
    const float* __restrict__ s_src, const float* __restrict__ s_dst,
    float* __restrict__ out) {
  __shared__ short Pbuf[2][16][PSTR];  // 16.5 KB: p-values, double-buffered
  __shared__ float part[8][16][64];    // 32 KB: per-wave partial numerators
  __shared__ float dden[16];           // full row denominators
  const int tid = threadIdx.x;
  const int w = tid >> 6;
  const int lane = tid & 63;
  const int m = lane & 15;
  const int quad = lane >> 4;
  const int bid = blockIdx.x;
  const int i0 = bid * 16;
  const int rA = 2 * w, rB = 2 * w + 1;
  const float ssA = s_src[i0 + rA];
  const float ssB = s_src[i0 + rB];
  const int* adjA = adj + (size_t)(i0 + rA) * NN + lane * 4;
  const int* adjB = adj + (size_t)(i0 + rB) * NN + lane * 4;
  const float* sdp = s_dst + lane * 4;

  floatx4 acc0 = {0.f, 0.f, 0.f, 0.f};
  floatx4 acc1 = acc0, acc2 = acc0, acc3 = acc0;
  float dsA = 0.f, dsB = 0.f;

  // ---- prologue: produce chunk cc(0) into buf0; load regs for chunk cc(1) ----
  int q = bid & (NCH - 1);
  intx4 aA = __builtin_nontemporal_load((const intx4*)(adjA + q * JCH));
  intx4 aB = __builtin_nontemporal_load((const intx4*)(adjB + q * JCH));
  float4 sv = *(const float4*)(sdp + q * JCH);
  *(short4v*)&Pbuf[0][rA][lane * 4] = pcalc(ssA, aA, sv, dsA);
  *(short4v*)&Pbuf[0][rB][lane * 4] = pcalc(ssB, aB, sv, dsB);
  q = (bid + 1) & (NCH - 1);
  aA = __builtin_nontemporal_load((const intx4*)(adjA + q * JCH));
  aB = __builtin_nontemporal_load((const intx4*)(adjB + q * JCH));
  sv = *(const float4*)(sdp + q * JCH);

  for (int c = 0; c < NCH; ++c) {
    // cheap barrier: drain LDS only; global prefetches stay in flight
    asm volatile("s_waitcnt lgkmcnt(0)\n\ts_barrier" ::: "memory");
    const int cc = (c + bid) & (NCH - 1);
    // 1) Hb B-fragments for this chunk's k-strip (L2-resident; issue FIRST)
    const short8* hp = Hb + (size_t)(cc * 8 + w) * 4 * 64 + lane;
    short8 h0 = hp[0], h1 = hp[64], h2 = hp[128], h3 = hp[192];
    // 2) produce chunk c+1 from regs loaded in iter c-1
    if (c + 1 < NCH) {
      short4v pA = pcalc(ssA, aA, sv, dsA);
      short4v pB = pcalc(ssB, aB, sv, dsB);
      *(short4v*)&Pbuf[(c + 1) & 1][rA][lane * 4] = pA;
      *(short4v*)&Pbuf[(c + 1) & 1][rB][lane * 4] = pB;
    }
    // 3) adj/s loads for chunk c+2 (slow HBM stream; newest in queue)
    if (c + 2 < NCH) {
      const int cn = (c + 2 + bid) & (NCH - 1);
      aA = __builtin_nontemporal_load((const intx4*)(adjA + cn * JCH));
      aB = __builtin_nontemporal_load((const intx4*)(adjB + cn * JCH));
      sv = *(const float4*)(sdp + cn * JCH);
    }
    // 4) A-fragment from LDS (written by all waves in iter c-1)
    short8 af = *(const short8*)&Pbuf[c & 1][m][w * 32 + quad * 8];
    // 5) MFMA: waits on Hb (older than adj(c+2) in queue -> no coupling)
    acc0 = __builtin_amdgcn_mfma_f32_16x16x32_bf16(af, h0, acc0, 0, 0, 0);
    acc1 = __builtin_amdgcn_mfma_f32_16x16x32_bf16(af, h1, acc1, 0, 0, 0);
    acc2 = __builtin_amdgcn_mfma_f32_16x16x32_bf16(af, h2, acc2, 0, 0, 0);
    acc3 = __builtin_amdgcn_mfma_f32_16x16x32_bf16(af, h3, acc3, 0, 0, 0);
  }

  // full row denominators: wave w produced ALL of rows 2w,2w+1
#pragma unroll
  for (int off = 1; off < 64; off <<= 1) {
    dsA += __shfl_xor(dsA, off, 64);
    dsB += __shfl_xor(dsB, off, 64);
  }
  if (lane == 0) { dden[rA] = dsA; dden[rB] = dsB; }

  // C/D layout: col = lane&15 (feature within tile), row = quad*4 + reg
  const int col = lane & 15;
#pragma unroll
  for (int rg = 0; rg < 4; ++rg) {
    part[w][quad * 4 + rg][col]      = acc0[rg];
    part[w][quad * 4 + rg][16 + col] = acc1[rg];
    part[w][quad * 4 + rg][32 + col] = acc2[rg];
    part[w][quad * 4 + rg][48 + col] = acc3[rg];
  }
  __syncthreads();

  // epilogue: sum 8 wave-partials (disjoint j), normalize, ELU, coalesced store
  for (int idx = tid; idx < 16 * 64; idx += 512) {
    int mr = idx >> 6, fc = idx & 63;
    float num = 0.f;
#pragma unroll
    for (int ww = 0; ww < 8; ++ww) num += part[ww][mr][fc];
    float o = num / dden[mr];
    o = (o > 0.f) ? o : (__expf(o) - 1.f);
    out[(size_t)(i0 + mr) * FOUT + fc] = o;
  }
}

extern "C" void kernel_launch(void* const* d_in, const int* in_sizes, int n_in,
                              void* d_out, int out_size, void* d_ws, size_t ws_size,
                              hipStream_t stream) {
  const float* x     = (const float*)d_in[0];
  const int*   adj   = (const int*)d_in[1];
  const float* W     = (const float*)d_in[2];
  const float* att_w = (const float*)d_in[3];
  float* out = (float*)d_out;
  char* ws = (char*)d_ws;
  short* Hb = (short*)ws;                                   // 1 MB bf16 swizzled h
  float* s_src = (float*)(ws + (size_t)NN * FOUT * sizeof(short));
  float* s_dst = s_src + NN;
  prep_kernel<<<NN / 16, 256, 0, stream>>>(x, W, att_w, Hb, s_src, s_dst);
  gat_kernel<<<NN / 16, 512, 0, stream>>>(adj, (const short8*)Hb, s_src, s_dst, out);
}